// Round 10
// baseline (492.714 us; speedup 1.0000x reference)
//
#include <hip/hip_runtime.h>
#include <cmath>

#define NN 50000
#define EE 800000
#define ETOT (EE + NN)
#define NSCAN ((NN + 1023) / 1024)
#define SROWS 50048   // padded rows for head-major logit arrays

typedef __bf16 v8bf __attribute__((ext_vector_type(8)));
typedef float f32x4 __attribute__((ext_vector_type(4)));
typedef float f32x2 __attribute__((ext_vector_type(2)));

__device__ __forceinline__ float lrelu(float x){ return x > 0.0f ? x : 0.2f * x; }
__device__ __forceinline__ unsigned short f2bf_rne(float x){
  unsigned int u = __float_as_uint(x);
  u += 0x7fffu + ((u >> 16) & 1u);
  return (unsigned short)(u >> 16);
}
__device__ __forceinline__ float bf2f(unsigned short b){
  return __uint_as_float(((unsigned int)b) << 16);
}
// packed accumulate: 4×f32x2 -> v_pk_fma_f32
__device__ __forceinline__ void fma8p(f32x2* acc, float w, uint4 u){
  f32x2 w2 = {w, w};
  f32x2 a0, a1, a2, a3;
  a0[0] = __uint_as_float(u.x << 16); a0[1] = __uint_as_float(u.x & 0xffff0000u);
  a1[0] = __uint_as_float(u.y << 16); a1[1] = __uint_as_float(u.y & 0xffff0000u);
  a2[0] = __uint_as_float(u.z << 16); a2[1] = __uint_as_float(u.z & 0xffff0000u);
  a3[0] = __uint_as_float(u.w << 16); a3[1] = __uint_as_float(u.w & 0xffff0000u);
  acc[0] += w2 * a0;
  acc[1] += w2 * a1;
  acc[2] += w2 * a2;
  acc[3] += w2 * a3;
}

// ---------------- CSR build ----------------
__global__ void k_hist(const int* __restrict__ dst, int* __restrict__ cnt){
  int i = blockIdx.x * 256 + threadIdx.x;
  if (i >= ETOT) return;
  int d = (i < EE) ? dst[i] : (i - EE);
  atomicAdd(&cnt[d], 1);
}

__global__ void k_scan1(const int* __restrict__ cnt, int* __restrict__ part){
  __shared__ int sm[256];
  int b = blockIdx.x, t = threadIdx.x;
  int base = b * 1024 + t * 4;
  int s = 0;
  #pragma unroll
  for (int j = 0; j < 4; j++) if (base + j < NN) s += cnt[base + j];
  sm[t] = s; __syncthreads();
  for (int off = 128; off; off >>= 1){
    if (t < off) sm[t] += sm[t + off];
    __syncthreads();
  }
  if (t == 0) part[b] = sm[0];
}

__global__ void k_scan2(const int* __restrict__ part, int* __restrict__ part2){
  if (threadIdx.x == 0 && blockIdx.x == 0){
    int run = 0;
    for (int i = 0; i < NSCAN; i++){ part2[i] = run; run += part[i]; }
  }
}

__global__ void k_scan3(const int* __restrict__ cnt, const int* __restrict__ part2,
                        int* __restrict__ rowptr){
  __shared__ int sm[256];
  int b = blockIdx.x, t = threadIdx.x;
  int base = b * 1024 + t * 4;
  int v[4]; int s = 0;
  #pragma unroll
  for (int j = 0; j < 4; j++){ v[j] = (base + j < NN) ? cnt[base + j] : 0; s += v[j]; }
  sm[t] = s; __syncthreads();
  for (int off = 1; off < 256; off <<= 1){
    int x = (t >= off) ? sm[t - off] : 0;
    __syncthreads();
    sm[t] += x;
    __syncthreads();
  }
  int run = part2[b] + sm[t] - s;
  #pragma unroll
  for (int j = 0; j < 4; j++){
    if (base + j < NN){ rowptr[base + j] = run; run += v[j]; }
  }
  if (b == 0 && t == 0) rowptr[NN] = ETOT;
}

__global__ void k_scatter(const int* __restrict__ src, const int* __restrict__ dst,
                          const int* __restrict__ rowptr, int* __restrict__ fill,
                          int* __restrict__ csr){
  int i = blockIdx.x * 256 + threadIdx.x;
  if (i >= ETOT) return;
  int s, d;
  if (i < EE){ s = src[i]; d = dst[i]; } else { s = d = i - EE; }
  int pos = rowptr[d] + atomicAdd(&fill[d], 1);
  csr[pos] = s;
}

// ---------------- weight conversion: fp32 [.,K,N] -> bf16 hi/lo [.,K/8,N,8] ----
__global__ void k_convB(const float* __restrict__ B, unsigned short* __restrict__ bh,
                        unsigned short* __restrict__ bl, int K, int N, int total){
  int i = blockIdx.x * 256 + threadIdx.x;
  if (i >= total) return;
  int per = K * N;
  int h = i / per, rem = i - h * per;
  int k = rem / N, n = rem - k * N;
  float x = B[i];
  unsigned short hb = f2bf_rne(x);
  unsigned short lb = f2bf_rne(x - bf2f(hb));
  size_t o = (size_t)h * per + ((size_t)(k >> 3) * N + n) * 8 + (k & 7);
  bh[o] = hb; bl[o] = lb;
}

// ---------------- split-bf16 MFMA GEMM (fp32 A), fused att row-dots ----------
// C-store goes through an LDS tile (aliasing the staging LDS) so global
// writes are stride-1 u32, 256B/wave-inst coalesced (was 64 scattered 2B
// stores per thread).
template<int BN, int OSTR>
__global__ __launch_bounds__(256) void gemm_split(const float* __restrict__ A,
                                                  const unsigned short* __restrict__ Bh,
                                                  const unsigned short* __restrict__ Bl,
                                                  unsigned short* __restrict__ out,
                                                  int M, int K,
                                                  const float* __restrict__ att_s,
                                                  const float* __restrict__ att_d,
                                                  float* __restrict__ ssrc,
                                                  float* __restrict__ sdst){
  constexpr int SB_BYTES = 4 * BN * 16;
  constexpr int SM_BYTES = 16384 + 2 * SB_BYTES;
  constexpr int CT_BYTES = 128 * BN * 2;
  constexpr int LDS_BYTES = SM_BYTES > CT_BYTES ? SM_BYTES : CT_BYTES;
  __shared__ __align__(16) char smem[LDS_BYTES];
  v8bf (*sAh)[128] = (v8bf(*)[128])(smem);
  v8bf (*sAl)[128] = (v8bf(*)[128])(smem + 8192);
  v8bf (*sBh)[BN]  = (v8bf(*)[BN])(smem + 16384);
  v8bf (*sBl)[BN]  = (v8bf(*)[BN])(smem + 16384 + SB_BYTES);

  const int t = threadIdx.x;
  const int wv = t >> 6, lane = t & 63;
  const int m0 = blockIdx.x * 128;
  const int h = blockIdx.y;
  A  += (size_t)h * M * K;
  Bh += (size_t)h * (K >> 3) * BN * 8;
  Bl += (size_t)h * (K >> 3) * BN * 8;
  const int colOff = h * BN;

  f32x4 acc[2][BN / 16];
  #pragma unroll
  for (int i = 0; i < 2; i++)
    #pragma unroll
    for (int j = 0; j < BN / 16; j++){
      f32x4 z = {0.f, 0.f, 0.f, 0.f};
      acc[i][j] = z;
    }

  const int mRow = t & 127;
  const int kh = (t >> 7) * 16;
  const bool valid = (m0 + mRow) < M;
  const int q = lane >> 4, lm = lane & 15;

  for (int k0 = 0; k0 < K; k0 += 32){
    const float* ap = A + (size_t)(m0 + mRow) * K + k0 + kh;
    float4 v0, v1, v2, v3;
    if (valid){
      v0 = *(const float4*)(ap);
      v1 = *(const float4*)(ap + 4);
      v2 = *(const float4*)(ap + 8);
      v3 = *(const float4*)(ap + 12);
    } else {
      v0 = v1 = v2 = v3 = make_float4(0.f, 0.f, 0.f, 0.f);
    }
    #pragma unroll
    for (int g = 0; g < 2; g++){
      float xv[8];
      if (g == 0){ xv[0]=v0.x; xv[1]=v0.y; xv[2]=v0.z; xv[3]=v0.w; xv[4]=v1.x; xv[5]=v1.y; xv[6]=v1.z; xv[7]=v1.w; }
      else       { xv[0]=v2.x; xv[1]=v2.y; xv[2]=v2.z; xv[3]=v2.w; xv[4]=v3.x; xv[5]=v3.y; xv[6]=v3.z; xv[7]=v3.w; }
      v8bf H, L;
      #pragma unroll
      for (int i = 0; i < 8; i++){
        __bf16 hb = (__bf16)xv[i];          // v_cvt_pk_bf16_f32 (paired), RNE
        float  hf = (float)hb;               // exact widen
        H[i] = hb;
        L[i] = (__bf16)(xv[i] - hf);
      }
      int k8 = (kh >> 3) + g;
      sAh[k8][mRow] = H;
      sAl[k8][mRow] = L;
    }
    {
      const v8bf* gh = (const v8bf*)Bh + (size_t)(k0 >> 3) * BN;
      const v8bf* gl = (const v8bf*)Bl + (size_t)(k0 >> 3) * BN;
      v8bf* dh = &sBh[0][0];
      v8bf* dl = &sBl[0][0];
      #pragma unroll
      for (int i = t; i < 4 * BN; i += 256){ dh[i] = gh[i]; dl[i] = gl[i]; }
    }
    __syncthreads();
    v8bf ah[2], al[2];
    #pragma unroll
    for (int rt = 0; rt < 2; rt++){
      int m = wv * 32 + rt * 16 + lm;
      ah[rt] = sAh[q][m];
      al[rt] = sAl[q][m];
    }
    #pragma unroll
    for (int ct = 0; ct < BN / 16; ct++){
      v8bf bh = sBh[q][ct * 16 + lm];
      v8bf bl = sBl[q][ct * 16 + lm];
      #pragma unroll
      for (int rt = 0; rt < 2; rt++){
        acc[rt][ct] = __builtin_amdgcn_mfma_f32_16x16x32_bf16(ah[rt], bh, acc[rt][ct], 0, 0, 0);
        acc[rt][ct] = __builtin_amdgcn_mfma_f32_16x16x32_bf16(ah[rt], bl, acc[rt][ct], 0, 0, 0);
        acc[rt][ct] = __builtin_amdgcn_mfma_f32_16x16x32_bf16(al[rt], bh, acc[rt][ct], 0, 0, 0);
      }
    }
    __syncthreads();
  }

  float asv[BN / 16], adv[BN / 16];
  #pragma unroll
  for (int ct = 0; ct < BN / 16; ct++){
    asv[ct] = att_s[h * BN + ct * 16 + lm];
    adv[ct] = att_d[h * BN + ct * 16 + lm];
  }

  // ---- fused att row-dots ----
  #pragma unroll
  for (int rt = 0; rt < 2; rt++){
    #pragma unroll
    for (int reg = 0; reg < 4; reg++){
      int r = m0 + wv * 32 + rt * 16 + q * 4 + reg;
      float d0 = 0.f, d1 = 0.f;
      #pragma unroll
      for (int ct = 0; ct < BN / 16; ct++){
        float v = acc[rt][ct][reg];
        d0 += v * asv[ct];
        d1 += v * adv[ct];
      }
      #pragma unroll
      for (int off = 1; off < 16; off <<= 1){
        d0 += __shfl_xor(d0, off, 64);
        d1 += __shfl_xor(d1, off, 64);
      }
      if (r < M && lm == 0){
        ssrc[(size_t)h * SROWS + r] = d0;
        sdst[(size_t)h * SROWS + r] = d1;
      }
    }
  }

  // ---- C-store via LDS tile (coalesced) ----
  unsigned short* ctile = (unsigned short*)smem;
  #pragma unroll
  for (int rt = 0; rt < 2; rt++)
    #pragma unroll
    for (int reg = 0; reg < 4; reg++){
      int lr = wv * 32 + rt * 16 + q * 4 + reg;
      #pragma unroll
      for (int ct = 0; ct < BN / 16; ct++)
        ctile[lr * BN + ct * 16 + lm] = f2bf_rne(acc[rt][ct][reg]);
    }
  __syncthreads();
  {
    const unsigned int* ct32 = (const unsigned int*)ctile;
    constexpr int W = BN / 2;          // u32 words per row
    constexpr int TOT = 128 * W;
    #pragma unroll
    for (int i = t; i < TOT; i += 256){
      int row = i / W, c2 = i - row * W;
      int r = m0 + row;
      if (r < M)
        *(unsigned int*)(out + (size_t)r * OSTR + colOff + c2 * 2) = ct32[i];
    }
  }
}

// ---------------- split-bf16 MFMA GEMM (pre-split bf16 A), fused row-dots ----
template<int BN, int OSTR>
__global__ __launch_bounds__(256) void gemm_ps(const unsigned short* __restrict__ Ah,
                                               const unsigned short* __restrict__ Al,
                                               const unsigned short* __restrict__ Bh,
                                               const unsigned short* __restrict__ Bl,
                                               unsigned short* __restrict__ out,
                                               int M, int K,
                                               const float* __restrict__ att_s,
                                               const float* __restrict__ att_d,
                                               float* __restrict__ ssrc,
                                               float* __restrict__ sdst){
  constexpr int SB_BYTES = 4 * BN * 16;
  constexpr int SM_BYTES = 16384 + 2 * SB_BYTES;
  constexpr int CT_BYTES = 128 * BN * 2;
  constexpr int LDS_BYTES = SM_BYTES > CT_BYTES ? SM_BYTES : CT_BYTES;
  __shared__ __align__(16) char smem[LDS_BYTES];
  v8bf (*sAh)[128] = (v8bf(*)[128])(smem);
  v8bf (*sAl)[128] = (v8bf(*)[128])(smem + 8192);
  v8bf (*sBh)[BN]  = (v8bf(*)[BN])(smem + 16384);
  v8bf (*sBl)[BN]  = (v8bf(*)[BN])(smem + 16384 + SB_BYTES);

  const int t = threadIdx.x;
  const int wv = t >> 6, lane = t & 63;
  const int m0 = blockIdx.x * 128;
  const int h = blockIdx.y;
  const int colOff = h * BN;

  f32x4 acc[2][BN / 16];
  #pragma unroll
  for (int i = 0; i < 2; i++)
    #pragma unroll
    for (int j = 0; j < BN / 16; j++){
      f32x4 z = {0.f, 0.f, 0.f, 0.f};
      acc[i][j] = z;
    }

  const int mRow = t & 127;
  const int kh = (t >> 7) * 16;
  const bool valid = (m0 + mRow) < M;
  const int q = lane >> 4, lm = lane & 15;

  for (int k0 = 0; k0 < K; k0 += 32){
    // ---- stage A: pure 16B copies, zero conversion VALU ----
    const unsigned short* aph = Ah + (size_t)(m0 + mRow) * K + k0 + kh;
    const unsigned short* apl = Al + (size_t)(m0 + mRow) * K + k0 + kh;
    uint4 h0, h1, l0, l1;
    if (valid){
      h0 = *(const uint4*)(aph);
      h1 = *(const uint4*)(aph + 8);
      l0 = *(const uint4*)(apl);
      l1 = *(const uint4*)(apl + 8);
    } else {
      h0 = h1 = l0 = l1 = make_uint4(0, 0, 0, 0);
    }
    int k8 = kh >> 3;
    sAh[k8][mRow]     = *(v8bf*)&h0;
    sAh[k8 + 1][mRow] = *(v8bf*)&h1;
    sAl[k8][mRow]     = *(v8bf*)&l0;
    sAl[k8 + 1][mRow] = *(v8bf*)&l1;
    {
      const v8bf* gh = (const v8bf*)Bh + (size_t)(k0 >> 3) * BN;
      const v8bf* gl = (const v8bf*)Bl + (size_t)(k0 >> 3) * BN;
      v8bf* dh = &sBh[0][0];
      v8bf* dl = &sBl[0][0];
      #pragma unroll
      for (int i = t; i < 4 * BN; i += 256){ dh[i] = gh[i]; dl[i] = gl[i]; }
    }
    __syncthreads();
    v8bf ah[2], al[2];
    #pragma unroll
    for (int rt = 0; rt < 2; rt++){
      int m = wv * 32 + rt * 16 + lm;
      ah[rt] = sAh[q][m];
      al[rt] = sAl[q][m];
    }
    #pragma unroll
    for (int ct = 0; ct < BN / 16; ct++){
      v8bf bh = sBh[q][ct * 16 + lm];
      v8bf bl = sBl[q][ct * 16 + lm];
      #pragma unroll
      for (int rt = 0; rt < 2; rt++){
        acc[rt][ct] = __builtin_amdgcn_mfma_f32_16x16x32_bf16(ah[rt], bh, acc[rt][ct], 0, 0, 0);
        acc[rt][ct] = __builtin_amdgcn_mfma_f32_16x16x32_bf16(ah[rt], bl, acc[rt][ct], 0, 0, 0);
        acc[rt][ct] = __builtin_amdgcn_mfma_f32_16x16x32_bf16(al[rt], bh, acc[rt][ct], 0, 0, 0);
      }
    }
    __syncthreads();
  }

  float asv[BN / 16], adv[BN / 16];
  #pragma unroll
  for (int ct = 0; ct < BN / 16; ct++){
    asv[ct] = att_s[h * BN + ct * 16 + lm];
    adv[ct] = att_d[h * BN + ct * 16 + lm];
  }

  #pragma unroll
  for (int rt = 0; rt < 2; rt++){
    #pragma unroll
    for (int reg = 0; reg < 4; reg++){
      int r = m0 + wv * 32 + rt * 16 + q * 4 + reg;
      float d0 = 0.f, d1 = 0.f;
      #pragma unroll
      for (int ct = 0; ct < BN / 16; ct++){
        float v = acc[rt][ct][reg];
        d0 += v * asv[ct];
        d1 += v * adv[ct];
      }
      #pragma unroll
      for (int off = 1; off < 16; off <<= 1){
        d0 += __shfl_xor(d0, off, 64);
        d1 += __shfl_xor(d1, off, 64);
      }
      if (r < M && lm == 0){
        ssrc[(size_t)h * SROWS + r] = d0;
        sdst[(size_t)h * SROWS + r] = d1;
      }
    }
  }

  // ---- C-store via LDS tile (coalesced) ----
  unsigned short* ctile = (unsigned short*)smem;
  #pragma unroll
  for (int rt = 0; rt < 2; rt++)
    #pragma unroll
    for (int reg = 0; reg < 4; reg++){
      int lr = wv * 32 + rt * 16 + q * 4 + reg;
      #pragma unroll
      for (int ct = 0; ct < BN / 16; ct++)
        ctile[lr * BN + ct * 16 + lm] = f2bf_rne(acc[rt][ct][reg]);
    }
  __syncthreads();
  {
    const unsigned int* ct32 = (const unsigned int*)ctile;
    constexpr int W = BN / 2;
    constexpr int TOT = 128 * W;
    #pragma unroll
    for (int i = t; i < TOT; i += 256){
      int row = i / W, c2 = i - row * W;
      int r = m0 + row;
      if (r < M)
        *(unsigned int*)(out + (size_t)r * OSTR + colOff + c2 * 2) = ct32[i];
    }
  }
}

// ---------------- layer-1 aggregation: 8-lane group per (node, head) --------
// Per-head grid.y (L2-friendly 12.8MB hot slice). 8 lanes/edge, 32B/lane ->
// 8 edges in flight per wave, ~28% fewer lane-instructions per edge than the
// 16-lane variant (less redundant exp/addr work). No shuffles in the edge
// loop (same-address broadcast of csr/ssrc); depth-2 pipeline; packed
// v_pk_fma_f32. sloc is the full denominator per-lane (no reduction).
__global__ __launch_bounds__(256) void k_agg1(const int* __restrict__ rowptr,
                                              const int* __restrict__ csr,
                                              const float* __restrict__ ssrc,
                                              const float* __restrict__ sdst,
                                              const unsigned short* __restrict__ xs_all,
                                              const float* __restrict__ bias,
                                              unsigned short* __restrict__ x1h,
                                              unsigned short* __restrict__ x1l){
  int tid = blockIdx.x * 256 + threadIdx.x;
  int n = tid >> 3;
  int lm = threadIdx.x & 7;
  int h = blockIdx.y;
  if (n >= NN) return;
  int start = rowptr[n], end = rowptr[n + 1];
  const float* sp = ssrc + (size_t)h * SROWS;
  float sdn = sdst[(size_t)h * SROWS + n];
  const uint4* xp = (const uint4*)xs_all + h * 16 + lm * 2;

  float sloc = 0.f;
  f32x2 acc[8];
  #pragma unroll
  for (int i = 0; i < 8; i++){ f32x2 z = {0.f, 0.f}; acc[i] = z; }

  // depth-2 pipeline: consume edge e while loading e+1
  int e = start;
  int sA = csr[e];
  float svA = sp[sA];
  uint4 uA0 = xp[(size_t)sA * 64], uA1 = xp[(size_t)sA * 64 + 1];
  for (; e + 1 < end; e++){
    int sB = csr[e + 1];
    float svB = sp[sB];
    uint4 uB0 = xp[(size_t)sB * 64], uB1 = xp[(size_t)sB * 64 + 1];
    float w = __expf(lrelu(svA + sdn));
    sloc += w;
    fma8p(acc, w, uA0);
    fma8p(acc + 4, w, uA1);
    svA = svB; uA0 = uB0; uA1 = uB1;
  }
  float w = __expf(lrelu(svA + sdn));
  sloc += w;
  fma8p(acc, w, uA0);
  fma8p(acc + 4, w, uA1);

  float inv = 1.f / sloc;

  const float* bp = bias + h * 128 + lm * 16;
  union { uint4 q[2]; unsigned short u[16]; } HH, LL;
  #pragma unroll
  for (int i = 0; i < 16; i++){
    float o = lrelu(acc[i >> 1][i & 1] * inv + bp[i]);
    unsigned short hb = f2bf_rne(o);
    HH.u[i] = hb;
    LL.u[i] = f2bf_rne(o - bf2f(hb));
  }
  size_t ofs = (size_t)n * 512 + h * 128 + lm * 16;
  *(uint4*)(x1h + ofs)        = HH.q[0];
  *((uint4*)(x1h + ofs) + 1)  = HH.q[1];
  *(uint4*)(x1l + ofs)        = LL.q[0];
  *((uint4*)(x1l + ofs) + 1)  = LL.q[1];
}

// ---------------- layer-2 aggregation: 4-lane group per node ------------------
// 4 lanes/edge, 32B/lane -> 16 edges in flight per wave. sloc is the full
// denominator per-lane.
__global__ __launch_bounds__(256) void k_agg2(const int* __restrict__ rowptr,
                                              const int* __restrict__ csr,
                                              const float* __restrict__ ssrc,
                                              const float* __restrict__ sdst,
                                              const unsigned short* __restrict__ xs2,
                                              const float* __restrict__ bias,
                                              float* __restrict__ outp){
  int tid = blockIdx.x * 256 + threadIdx.x;
  int n = tid >> 2;
  int lm = threadIdx.x & 3;
  if (n >= NN) return;
  int start = rowptr[n], end = rowptr[n + 1];
  float sdn = sdst[n];
  const uint4* xp = (const uint4*)xs2 + lm * 2;

  float sloc = 0.f;
  f32x2 acc[8];
  #pragma unroll
  for (int i = 0; i < 8; i++){ f32x2 z = {0.f, 0.f}; acc[i] = z; }

  int e = start;
  int sA = csr[e];
  float svA = ssrc[sA];
  uint4 uA0 = xp[(size_t)sA * 8], uA1 = xp[(size_t)sA * 8 + 1];
  for (; e + 1 < end; e++){
    int sB = csr[e + 1];
    float svB = ssrc[sB];
    uint4 uB0 = xp[(size_t)sB * 8], uB1 = xp[(size_t)sB * 8 + 1];
    float w = __expf(lrelu(svA + sdn));
    sloc += w;
    fma8p(acc, w, uA0);
    fma8p(acc + 4, w, uA1);
    svA = svB; uA0 = uB0; uA1 = uB1;
  }
  float w = __expf(lrelu(svA + sdn));
  sloc += w;
  fma8p(acc, w, uA0);
  fma8p(acc + 4, w, uA1);

  float inv = 1.f / sloc;

  const float* bp = bias + lm * 16;
  float o[16];
  #pragma unroll
  for (int i = 0; i < 16; i++)
    o[i] = tanhf(lrelu(acc[i >> 1][i & 1] * inv + bp[i]));
  float* op = outp + (size_t)n * 64 + lm * 16;
  *(float4*)op        = make_float4(o[0],  o[1],  o[2],  o[3]);
  *(float4*)(op + 4)  = make_float4(o[4],  o[5],  o[6],  o[7]);
  *(float4*)(op + 8)  = make_float4(o[8],  o[9],  o[10], o[11]);
  *(float4*)(op + 12) = make_float4(o[12], o[13], o[14], o[15]);
}

extern "C" void kernel_launch(void* const* d_in, const int* in_sizes, int n_in,
                              void* d_out, int out_size, void* d_ws, size_t ws_size,
                              hipStream_t stream){
  const float* type_emb  = (const float*)d_in[0];
  const int*   edge      = (const int*)d_in[1];
  const float* W         = (const float*)d_in[2];
  const float* att_src   = (const float*)d_in[3];
  const float* att_dst   = (const float*)d_in[4];
  const float* bias      = (const float*)d_in[5];
  const float* W_out     = (const float*)d_in[6];
  const float* att_src_o = (const float*)d_in[7];
  const float* att_dst_o = (const float*)d_in[8];
  const float* bias_o    = (const float*)d_in[9];
  float* out = (float*)d_out;
  (void)in_sizes; (void)n_in; (void)out_size; (void)ws_size;

  char* ws = (char*)d_ws;
  size_t off = 0;
  auto alloc = [&](size_t bytes) -> void* {
    void* p = ws + off;
    off = (off + bytes + 255) & ~(size_t)255;
    return p;
  };
  unsigned short* xs_all = (unsigned short*)alloc((size_t)NN * 512 * 2); // [N][4*128] bf16
  unsigned short* x1h    = (unsigned short*)alloc((size_t)NN * 512 * 2); // [N][512] bf16 hi
  unsigned short* x1l    = (unsigned short*)alloc((size_t)NN * 512 * 2); // [N][512] bf16 lo
  unsigned short* xs2    = (unsigned short*)alloc((size_t)NN * 64 * 2);  // [N][64] bf16
  float* ssrc1 = (float*)alloc((size_t)4 * SROWS * 4);  // head-major [4][SROWS]
  float* sdst1 = (float*)alloc((size_t)4 * SROWS * 4);
  float* ssrc2 = (float*)alloc((size_t)SROWS * 4);
  float* sdst2 = (float*)alloc((size_t)SROWS * 4);
  int* cnt    = (int*)alloc((size_t)NN * 4);
  int* rowptr = (int*)alloc((size_t)(NN + 1) * 4);
  int* fill   = (int*)alloc((size_t)NN * 4);
  int* csr    = (int*)alloc((size_t)ETOT * 4);
  int* p1     = (int*)alloc((size_t)NSCAN * 4 + 256);
  int* p2     = (int*)alloc((size_t)NSCAN * 4 + 256);
  unsigned short* Bh1 = (unsigned short*)alloc((size_t)4 * 128 * 128 * 2);
  unsigned short* Bl1 = (unsigned short*)alloc((size_t)4 * 128 * 128 * 2);
  unsigned short* Bh2 = (unsigned short*)alloc((size_t)512 * 64 * 2);
  unsigned short* Bl2 = (unsigned short*)alloc((size_t)512 * 64 * 2);

  // ---- CSR build (dst-sorted) ----
  hipMemsetAsync(cnt, 0, (size_t)NN * 4, stream);
  hipMemsetAsync(fill, 0, (size_t)NN * 4, stream);
  k_hist<<<(ETOT + 255) / 256, 256, 0, stream>>>(edge + EE, cnt);
  k_scan1<<<NSCAN, 256, 0, stream>>>(cnt, p1);
  k_scan2<<<1, 64, 0, stream>>>(p1, p2);
  k_scan3<<<NSCAN, 256, 0, stream>>>(cnt, p2, rowptr);
  k_scatter<<<(ETOT + 255) / 256, 256, 0, stream>>>(edge, edge + EE, rowptr, fill, csr);

  // ---- weight conversion ----
  k_convB<<<(4 * 128 * 128 + 255) / 256, 256, 0, stream>>>(W, Bh1, Bl1, 128, 128, 4 * 128 * 128);
  k_convB<<<(512 * 64 + 255) / 256, 256, 0, stream>>>(W_out, Bh2, Bl2, 512, 64, 512 * 64);

  // ---- layer 1: all 4 heads (GEMM + fused att row-dots) ----
  gemm_split<128, 512><<<dim3(391, 4), 256, 0, stream>>>(
      type_emb, Bh1, Bl1, xs_all, NN, 128, att_src, att_dst, ssrc1, sdst1);
  k_agg1<<<dim3(1563, 4), 256, 0, stream>>>(rowptr, csr, ssrc1, sdst1, xs_all, bias, x1h, x1l);

  // ---- layer 2 (pre-split A: zero staging conversion) ----
  gemm_ps<64, 64><<<dim3(391, 1), 256, 0, stream>>>(
      x1h, x1l, Bh2, Bl2, xs2, NN, 512, att_src_o, att_dst_o, ssrc2, sdst2);
  k_agg2<<<782, 256, 0, stream>>>(rowptr, csr, ssrc2, sdst2, xs2, bias_o, out);
}

// Round 11
// 441.510 us; speedup vs baseline: 1.1160x; 1.1160x over previous
//
#include <hip/hip_runtime.h>
#include <cmath>

#define NN 50000
#define EE 800000
#define ETOT (EE + NN)
#define NSCAN ((NN + 1023) / 1024)
#define SROWS 50048   // padded rows for head-major logit arrays

typedef __bf16 v8bf __attribute__((ext_vector_type(8)));
typedef float f32x4 __attribute__((ext_vector_type(4)));
typedef float f32x2 __attribute__((ext_vector_type(2)));

__device__ __forceinline__ float lrelu(float x){ return x > 0.0f ? x : 0.2f * x; }
__device__ __forceinline__ unsigned short f2bf_rne(float x){
  unsigned int u = __float_as_uint(x);
  u += 0x7fffu + ((u >> 16) & 1u);
  return (unsigned short)(u >> 16);
}
__device__ __forceinline__ float bf2f(unsigned short b){
  return __uint_as_float(((unsigned int)b) << 16);
}
// packed accumulate: acc[4] of float2 -> v_pk_fma_f32
__device__ __forceinline__ void fma8p(f32x2* acc, float w, uint4 u){
  f32x2 w2 = {w, w};
  f32x2 a0, a1, a2, a3;
  a0[0] = __uint_as_float(u.x << 16); a0[1] = __uint_as_float(u.x & 0xffff0000u);
  a1[0] = __uint_as_float(u.y << 16); a1[1] = __uint_as_float(u.y & 0xffff0000u);
  a2[0] = __uint_as_float(u.z << 16); a2[1] = __uint_as_float(u.z & 0xffff0000u);
  a3[0] = __uint_as_float(u.w << 16); a3[1] = __uint_as_float(u.w & 0xffff0000u);
  acc[0] += w2 * a0;
  acc[1] += w2 * a1;
  acc[2] += w2 * a2;
  acc[3] += w2 * a3;
}

// ---------------- CSR build ----------------
__global__ void k_hist(const int* __restrict__ dst, int* __restrict__ cnt){
  int i = blockIdx.x * 256 + threadIdx.x;
  if (i >= ETOT) return;
  int d = (i < EE) ? dst[i] : (i - EE);
  atomicAdd(&cnt[d], 1);
}

__global__ void k_scan1(const int* __restrict__ cnt, int* __restrict__ part){
  __shared__ int sm[256];
  int b = blockIdx.x, t = threadIdx.x;
  int base = b * 1024 + t * 4;
  int s = 0;
  #pragma unroll
  for (int j = 0; j < 4; j++) if (base + j < NN) s += cnt[base + j];
  sm[t] = s; __syncthreads();
  for (int off = 128; off; off >>= 1){
    if (t < off) sm[t] += sm[t + off];
    __syncthreads();
  }
  if (t == 0) part[b] = sm[0];
}

__global__ void k_scan2(const int* __restrict__ part, int* __restrict__ part2){
  if (threadIdx.x == 0 && blockIdx.x == 0){
    int run = 0;
    for (int i = 0; i < NSCAN; i++){ part2[i] = run; run += part[i]; }
  }
}

__global__ void k_scan3(const int* __restrict__ cnt, const int* __restrict__ part2,
                        int* __restrict__ rowptr){
  __shared__ int sm[256];
  int b = blockIdx.x, t = threadIdx.x;
  int base = b * 1024 + t * 4;
  int v[4]; int s = 0;
  #pragma unroll
  for (int j = 0; j < 4; j++){ v[j] = (base + j < NN) ? cnt[base + j] : 0; s += v[j]; }
  sm[t] = s; __syncthreads();
  for (int off = 1; off < 256; off <<= 1){
    int x = (t >= off) ? sm[t - off] : 0;
    __syncthreads();
    sm[t] += x;
    __syncthreads();
  }
  int run = part2[b] + sm[t] - s;
  #pragma unroll
  for (int j = 0; j < 4; j++){
    if (base + j < NN){ rowptr[base + j] = run; run += v[j]; }
  }
  if (b == 0 && t == 0) rowptr[NN] = ETOT;
}

__global__ void k_scatter(const int* __restrict__ src, const int* __restrict__ dst,
                          const int* __restrict__ rowptr, int* __restrict__ fill,
                          int* __restrict__ csr){
  int i = blockIdx.x * 256 + threadIdx.x;
  if (i >= ETOT) return;
  int s, d;
  if (i < EE){ s = src[i]; d = dst[i]; } else { s = d = i - EE; }
  int pos = rowptr[d] + atomicAdd(&fill[d], 1);
  csr[pos] = s;
}

// ---------------- weight conversion: fp32 [.,K,N] -> bf16 hi/lo [.,K/8,N,8] ----
__global__ void k_convB(const float* __restrict__ B, unsigned short* __restrict__ bh,
                        unsigned short* __restrict__ bl, int K, int N, int total){
  int i = blockIdx.x * 256 + threadIdx.x;
  if (i >= total) return;
  int per = K * N;
  int h = i / per, rem = i - h * per;
  int k = rem / N, n = rem - k * N;
  float x = B[i];
  unsigned short hb = f2bf_rne(x);
  unsigned short lb = f2bf_rne(x - bf2f(hb));
  size_t o = (size_t)h * per + ((size_t)(k >> 3) * N + n) * 8 + (k & 7);
  bh[o] = hb; bl[o] = lb;
}

// ---------------- split-bf16 MFMA GEMM (fp32 A), fused att row-dots ----------
// Staging uses native __bf16 casts -> v_cvt_pk_bf16_f32 (2 values/inst, RNE).
template<int BN, int OSTR>
__global__ __launch_bounds__(256) void gemm_split(const float* __restrict__ A,
                                                  const unsigned short* __restrict__ Bh,
                                                  const unsigned short* __restrict__ Bl,
                                                  unsigned short* __restrict__ out,
                                                  int M, int K,
                                                  const float* __restrict__ att_s,
                                                  const float* __restrict__ att_d,
                                                  float* __restrict__ ssrc,
                                                  float* __restrict__ sdst){
  const int t = threadIdx.x;
  const int wv = t >> 6, lane = t & 63;
  const int m0 = blockIdx.x * 128;
  const int h = blockIdx.y;
  A  += (size_t)h * M * K;
  Bh += (size_t)h * (K >> 3) * BN * 8;
  Bl += (size_t)h * (K >> 3) * BN * 8;
  const int colOff = h * BN;

  __shared__ v8bf sAh[4][128];
  __shared__ v8bf sAl[4][128];
  __shared__ v8bf sBh[4][BN];
  __shared__ v8bf sBl[4][BN];

  f32x4 acc[2][BN / 16];
  #pragma unroll
  for (int i = 0; i < 2; i++)
    #pragma unroll
    for (int j = 0; j < BN / 16; j++){
      f32x4 z = {0.f, 0.f, 0.f, 0.f};
      acc[i][j] = z;
    }

  const int mRow = t & 127;
  const int kh = (t >> 7) * 16;
  const bool valid = (m0 + mRow) < M;
  const int q = lane >> 4, lm = lane & 15;

  for (int k0 = 0; k0 < K; k0 += 32){
    const float* ap = A + (size_t)(m0 + mRow) * K + k0 + kh;
    float4 v0, v1, v2, v3;
    if (valid){
      v0 = *(const float4*)(ap);
      v1 = *(const float4*)(ap + 4);
      v2 = *(const float4*)(ap + 8);
      v3 = *(const float4*)(ap + 12);
    } else {
      v0 = v1 = v2 = v3 = make_float4(0.f, 0.f, 0.f, 0.f);
    }
    #pragma unroll
    for (int g = 0; g < 2; g++){
      float xv[8];
      if (g == 0){ xv[0]=v0.x; xv[1]=v0.y; xv[2]=v0.z; xv[3]=v0.w; xv[4]=v1.x; xv[5]=v1.y; xv[6]=v1.z; xv[7]=v1.w; }
      else       { xv[0]=v2.x; xv[1]=v2.y; xv[2]=v2.z; xv[3]=v2.w; xv[4]=v3.x; xv[5]=v3.y; xv[6]=v3.z; xv[7]=v3.w; }
      v8bf H, L;
      #pragma unroll
      for (int i = 0; i < 8; i++){
        __bf16 hb = (__bf16)xv[i];          // v_cvt_pk_bf16_f32 (paired), RNE
        float  hf = (float)hb;               // exact widen
        H[i] = hb;
        L[i] = (__bf16)(xv[i] - hf);
      }
      int k8 = (kh >> 3) + g;
      sAh[k8][mRow] = H;
      sAl[k8][mRow] = L;
    }
    {
      const v8bf* gh = (const v8bf*)Bh + (size_t)(k0 >> 3) * BN;
      const v8bf* gl = (const v8bf*)Bl + (size_t)(k0 >> 3) * BN;
      v8bf* dh = &sBh[0][0];
      v8bf* dl = &sBl[0][0];
      #pragma unroll
      for (int i = t; i < 4 * BN; i += 256){ dh[i] = gh[i]; dl[i] = gl[i]; }
    }
    __syncthreads();
    v8bf ah[2], al[2];
    #pragma unroll
    for (int rt = 0; rt < 2; rt++){
      int m = wv * 32 + rt * 16 + lm;
      ah[rt] = sAh[q][m];
      al[rt] = sAl[q][m];
    }
    #pragma unroll
    for (int ct = 0; ct < BN / 16; ct++){
      v8bf bh = sBh[q][ct * 16 + lm];
      v8bf bl = sBl[q][ct * 16 + lm];
      #pragma unroll
      for (int rt = 0; rt < 2; rt++){
        acc[rt][ct] = __builtin_amdgcn_mfma_f32_16x16x32_bf16(ah[rt], bh, acc[rt][ct], 0, 0, 0);
        acc[rt][ct] = __builtin_amdgcn_mfma_f32_16x16x32_bf16(ah[rt], bl, acc[rt][ct], 0, 0, 0);
        acc[rt][ct] = __builtin_amdgcn_mfma_f32_16x16x32_bf16(al[rt], bh, acc[rt][ct], 0, 0, 0);
      }
    }
    __syncthreads();
  }

  float asv[BN / 16], adv[BN / 16];
  #pragma unroll
  for (int ct = 0; ct < BN / 16; ct++){
    asv[ct] = att_s[h * BN + ct * 16 + lm];
    adv[ct] = att_d[h * BN + ct * 16 + lm];
  }

  #pragma unroll
  for (int rt = 0; rt < 2; rt++){
    #pragma unroll
    for (int reg = 0; reg < 4; reg++){
      int r = m0 + wv * 32 + rt * 16 + q * 4 + reg;
      float d0 = 0.f, d1 = 0.f;
      #pragma unroll
      for (int ct = 0; ct < BN / 16; ct++){
        float v = acc[rt][ct][reg];
        d0 += v * asv[ct];
        d1 += v * adv[ct];
      }
      #pragma unroll
      for (int off = 1; off < 16; off <<= 1){
        d0 += __shfl_xor(d0, off, 64);
        d1 += __shfl_xor(d1, off, 64);
      }
      if (r < M){
        unsigned short* orow = out + (size_t)r * OSTR + colOff + lm;
        #pragma unroll
        for (int ct = 0; ct < BN / 16; ct++)
          orow[ct * 16] = f2bf_rne(acc[rt][ct][reg]);
        if (lm == 0){
          ssrc[(size_t)h * SROWS + r] = d0;
          sdst[(size_t)h * SROWS + r] = d1;
        }
      }
    }
  }
}

// ---------------- bf16-A MFMA GEMM (A single bf16, B split hi/lo) ----------
// x1 precision: A carries one bf16 rounding (analysis: adds <=~3e-3 to final
// absmax vs 1e-2 threshold). 2 MFMA per step instead of 3; A staging halves.
template<int BN, int OSTR>
__global__ __launch_bounds__(256) void gemm_ps(const unsigned short* __restrict__ Ah,
                                               const unsigned short* __restrict__ Bh,
                                               const unsigned short* __restrict__ Bl,
                                               unsigned short* __restrict__ out,
                                               int M, int K,
                                               const float* __restrict__ att_s,
                                               const float* __restrict__ att_d,
                                               float* __restrict__ ssrc,
                                               float* __restrict__ sdst){
  const int t = threadIdx.x;
  const int wv = t >> 6, lane = t & 63;
  const int m0 = blockIdx.x * 128;
  const int h = blockIdx.y;
  const int colOff = h * BN;

  __shared__ v8bf sAh[4][128];
  __shared__ v8bf sBh[4][BN];
  __shared__ v8bf sBl[4][BN];

  f32x4 acc[2][BN / 16];
  #pragma unroll
  for (int i = 0; i < 2; i++)
    #pragma unroll
    for (int j = 0; j < BN / 16; j++){
      f32x4 z = {0.f, 0.f, 0.f, 0.f};
      acc[i][j] = z;
    }

  const int mRow = t & 127;
  const int kh = (t >> 7) * 16;
  const bool valid = (m0 + mRow) < M;
  const int q = lane >> 4, lm = lane & 15;

  for (int k0 = 0; k0 < K; k0 += 32){
    // ---- stage A: pure 16B copies ----
    const unsigned short* aph = Ah + (size_t)(m0 + mRow) * K + k0 + kh;
    uint4 h0, h1;
    if (valid){
      h0 = *(const uint4*)(aph);
      h1 = *(const uint4*)(aph + 8);
    } else {
      h0 = h1 = make_uint4(0, 0, 0, 0);
    }
    int k8 = kh >> 3;
    sAh[k8][mRow]     = *(v8bf*)&h0;
    sAh[k8 + 1][mRow] = *(v8bf*)&h1;
    {
      const v8bf* gh = (const v8bf*)Bh + (size_t)(k0 >> 3) * BN;
      const v8bf* gl = (const v8bf*)Bl + (size_t)(k0 >> 3) * BN;
      v8bf* dh = &sBh[0][0];
      v8bf* dl = &sBl[0][0];
      #pragma unroll
      for (int i = t; i < 4 * BN; i += 256){ dh[i] = gh[i]; dl[i] = gl[i]; }
    }
    __syncthreads();
    v8bf ah[2];
    #pragma unroll
    for (int rt = 0; rt < 2; rt++){
      int m = wv * 32 + rt * 16 + lm;
      ah[rt] = sAh[q][m];
    }
    #pragma unroll
    for (int ct = 0; ct < BN / 16; ct++){
      v8bf bh = sBh[q][ct * 16 + lm];
      v8bf bl = sBl[q][ct * 16 + lm];
      #pragma unroll
      for (int rt = 0; rt < 2; rt++){
        acc[rt][ct] = __builtin_amdgcn_mfma_f32_16x16x32_bf16(ah[rt], bh, acc[rt][ct], 0, 0, 0);
        acc[rt][ct] = __builtin_amdgcn_mfma_f32_16x16x32_bf16(ah[rt], bl, acc[rt][ct], 0, 0, 0);
      }
    }
    __syncthreads();
  }

  float asv[BN / 16], adv[BN / 16];
  #pragma unroll
  for (int ct = 0; ct < BN / 16; ct++){
    asv[ct] = att_s[h * BN + ct * 16 + lm];
    adv[ct] = att_d[h * BN + ct * 16 + lm];
  }

  #pragma unroll
  for (int rt = 0; rt < 2; rt++){
    #pragma unroll
    for (int reg = 0; reg < 4; reg++){
      int r = m0 + wv * 32 + rt * 16 + q * 4 + reg;
      float d0 = 0.f, d1 = 0.f;
      #pragma unroll
      for (int ct = 0; ct < BN / 16; ct++){
        float v = acc[rt][ct][reg];
        d0 += v * asv[ct];
        d1 += v * adv[ct];
      }
      #pragma unroll
      for (int off = 1; off < 16; off <<= 1){
        d0 += __shfl_xor(d0, off, 64);
        d1 += __shfl_xor(d1, off, 64);
      }
      if (r < M){
        unsigned short* orow = out + (size_t)r * OSTR + colOff + lm;
        #pragma unroll
        for (int ct = 0; ct < BN / 16; ct++)
          orow[ct * 16] = f2bf_rne(acc[rt][ct][reg]);
        if (lm == 0){
          ssrc[(size_t)h * SROWS + r] = d0;
          sdst[(size_t)h * SROWS + r] = d1;
        }
      }
    }
  }
}

// ---------------- layer-1 aggregation: 16-lane group per (node, head) --------
// Round-4/9 structure (proven locality optimum): per-head grid.y (12.8MB hot
// slice), 4 nodes/wave, no shuffles (same-address broadcast of csr/ssrc),
// depth-2 pipeline, packed v_pk_fma_f32. x1 written as SINGLE bf16 (hi only).
__global__ __launch_bounds__(256) void k_agg1(const int* __restrict__ rowptr,
                                              const int* __restrict__ csr,
                                              const float* __restrict__ ssrc,
                                              const float* __restrict__ sdst,
                                              const unsigned short* __restrict__ xs_all,
                                              const float* __restrict__ bias,
                                              unsigned short* __restrict__ x1h){
  int tid = blockIdx.x * 256 + threadIdx.x;
  int n = tid >> 4;
  int lm = threadIdx.x & 15;
  int h = blockIdx.y;
  if (n >= NN) return;
  int start = rowptr[n], end = rowptr[n + 1];
  const float* sp = ssrc + (size_t)h * SROWS;
  float sdn = sdst[(size_t)h * SROWS + n];
  const uint4* xp = (const uint4*)xs_all + h * 16 + lm;

  float sloc = 0.f;
  f32x2 acc[4];
  #pragma unroll
  for (int i = 0; i < 4; i++){ f32x2 z = {0.f, 0.f}; acc[i] = z; }

  // depth-2 pipeline: consume edge e while loading e+1
  int e = start;
  int sA = csr[e];
  float svA = sp[sA];
  uint4 uA = xp[(size_t)sA * 64];
  for (; e + 1 < end; e++){
    int sB = csr[e + 1];
    float svB = sp[sB];
    uint4 uB = xp[(size_t)sB * 64];
    float w = __expf(lrelu(svA + sdn));
    sloc += w;
    fma8p(acc, w, uA);
    svA = svB; uA = uB;
  }
  float w = __expf(lrelu(svA + sdn));
  sloc += w;
  fma8p(acc, w, uA);

  float inv = 1.f / sloc;

  const float* bp = bias + h * 128 + lm * 8;
  float4 b0 = *(const float4*)bp, b1 = *(const float4*)(bp + 4);
  float bb[8] = {b0.x, b0.y, b0.z, b0.w, b1.x, b1.y, b1.z, b1.w};
  union { uint4 q; unsigned short u[8]; } HH;
  #pragma unroll
  for (int i = 0; i < 8; i++){
    float o = lrelu(acc[i >> 1][i & 1] * inv + bb[i]);
    HH.u[i] = f2bf_rne(o);
  }
  size_t ofs = (size_t)n * 512 + h * 128 + lm * 8;
  *(uint4*)(x1h + ofs) = HH.q;
}

// ---------------- layer-2 aggregation: 8-lane group per node ------------------
// Round-4/9 structure + packed fma. sloc is full denominator per-lane.
__global__ __launch_bounds__(256) void k_agg2(const int* __restrict__ rowptr,
                                              const int* __restrict__ csr,
                                              const float* __restrict__ ssrc,
                                              const float* __restrict__ sdst,
                                              const unsigned short* __restrict__ xs2,
                                              const float* __restrict__ bias,
                                              float* __restrict__ outp){
  int tid = blockIdx.x * 256 + threadIdx.x;
  int n = tid >> 3;
  int lm = threadIdx.x & 7;
  if (n >= NN) return;
  int start = rowptr[n], end = rowptr[n + 1];
  float sdn = sdst[n];
  const uint4* xp = (const uint4*)xs2 + lm;

  float sloc = 0.f;
  f32x2 acc[4];
  #pragma unroll
  for (int i = 0; i < 4; i++){ f32x2 z = {0.f, 0.f}; acc[i] = z; }

  int e = start;
  int sA = csr[e];
  float svA = ssrc[sA];
  uint4 uA = xp[(size_t)sA * 8];
  for (; e + 1 < end; e++){
    int sB = csr[e + 1];
    float svB = ssrc[sB];
    uint4 uB = xp[(size_t)sB * 8];
    float w = __expf(lrelu(svA + sdn));
    sloc += w;
    fma8p(acc, w, uA);
    svA = svB; uA = uB;
  }
  float w = __expf(lrelu(svA + sdn));
  sloc += w;
  fma8p(acc, w, uA);

  float inv = 1.f / sloc;

  float o[8];
  #pragma unroll
  for (int i = 0; i < 8; i++)
    o[i] = tanhf(lrelu(acc[i >> 1][i & 1] * inv + bias[lm * 8 + i]));
  float* op = outp + (size_t)n * 64 + lm * 8;
  *(float4*)op       = make_float4(o[0], o[1], o[2], o[3]);
  *(float4*)(op + 4) = make_float4(o[4], o[5], o[6], o[7]);
}

extern "C" void kernel_launch(void* const* d_in, const int* in_sizes, int n_in,
                              void* d_out, int out_size, void* d_ws, size_t ws_size,
                              hipStream_t stream){
  const float* type_emb  = (const float*)d_in[0];
  const int*   edge      = (const int*)d_in[1];
  const float* W         = (const float*)d_in[2];
  const float* att_src   = (const float*)d_in[3];
  const float* att_dst   = (const float*)d_in[4];
  const float* bias      = (const float*)d_in[5];
  const float* W_out     = (const float*)d_in[6];
  const float* att_src_o = (const float*)d_in[7];
  const float* att_dst_o = (const float*)d_in[8];
  const float* bias_o    = (const float*)d_in[9];
  float* out = (float*)d_out;
  (void)in_sizes; (void)n_in; (void)out_size; (void)ws_size;

  char* ws = (char*)d_ws;
  size_t off = 0;
  auto alloc = [&](size_t bytes) -> void* {
    void* p = ws + off;
    off = (off + bytes + 255) & ~(size_t)255;
    return p;
  };
  unsigned short* xs_all = (unsigned short*)alloc((size_t)NN * 512 * 2); // [N][4*128] bf16
  unsigned short* x1h    = (unsigned short*)alloc((size_t)NN * 512 * 2); // [N][512] bf16
  unsigned short* xs2    = (unsigned short*)alloc((size_t)NN * 64 * 2);  // [N][64] bf16
  float* ssrc1 = (float*)alloc((size_t)4 * SROWS * 4);  // head-major [4][SROWS]
  float* sdst1 = (float*)alloc((size_t)4 * SROWS * 4);
  float* ssrc2 = (float*)alloc((size_t)SROWS * 4);
  float* sdst2 = (float*)alloc((size_t)SROWS * 4);
  int* cnt    = (int*)alloc((size_t)NN * 4);
  int* rowptr = (int*)alloc((size_t)(NN + 1) * 4);
  int* fill   = (int*)alloc((size_t)NN * 4);
  int* csr    = (int*)alloc((size_t)ETOT * 4);
  int* p1     = (int*)alloc((size_t)NSCAN * 4 + 256);
  int* p2     = (int*)alloc((size_t)NSCAN * 4 + 256);
  unsigned short* Bh1 = (unsigned short*)alloc((size_t)4 * 128 * 128 * 2);
  unsigned short* Bl1 = (unsigned short*)alloc((size_t)4 * 128 * 128 * 2);
  unsigned short* Bh2 = (unsigned short*)alloc((size_t)512 * 64 * 2);
  unsigned short* Bl2 = (unsigned short*)alloc((size_t)512 * 64 * 2);

  // ---- CSR build (dst-sorted) ----
  hipMemsetAsync(cnt, 0, (size_t)NN * 4, stream);
  hipMemsetAsync(fill, 0, (size_t)NN * 4, stream);
  k_hist<<<(ETOT + 255) / 256, 256, 0, stream>>>(edge + EE, cnt);
  k_scan1<<<NSCAN, 256, 0, stream>>>(cnt, p1);
  k_scan2<<<1, 64, 0, stream>>>(p1, p2);
  k_scan3<<<NSCAN, 256, 0, stream>>>(cnt, p2, rowptr);
  k_scatter<<<(ETOT + 255) / 256, 256, 0, stream>>>(edge, edge + EE, rowptr, fill, csr);

  // ---- weight conversion ----
  k_convB<<<(4 * 128 * 128 + 255) / 256, 256, 0, stream>>>(W, Bh1, Bl1, 128, 128, 4 * 128 * 128);
  k_convB<<<(512 * 64 + 255) / 256, 256, 0, stream>>>(W_out, Bh2, Bl2, 512, 64, 512 * 64);

  // ---- layer 1: all 4 heads (GEMM + fused att row-dots) ----
  gemm_split<128, 512><<<dim3(391, 4), 256, 0, stream>>>(
      type_emb, Bh1, Bl1, xs_all, NN, 128, att_src, att_dst, ssrc1, sdst1);
  k_agg1<<<dim3(3125, 4), 256, 0, stream>>>(rowptr, csr, ssrc1, sdst1, xs_all, bias, x1h);

  // ---- layer 2 (bf16 A, split B) ----
  gemm_ps<64, 64><<<dim3(391, 1), 256, 0, stream>>>(
      x1h, Bh2, Bl2, xs2, NN, 512, att_src_o, att_dst_o, ssrc2, sdst2);
  k_agg2<<<1563, 256, 0, stream>>>(rowptr, csr, ssrc2, sdst2, xs2, bias_o, out);
}